// Round 11
// baseline (205.250 us; speedup 1.0000x reference)
//
#include <hip/hip_runtime.h>

#define TT 16384      // tokens
#define DD 1024
#define HH 512
#define EE 8
#define NA (2*TT)                  // assignments
#define NBLK (NA/256)              // 128 hist blocks
#define SLOT_CAP (NA + EE*128)     // 33792
#define MT_TILES (SLOT_CAP/128)    // 264 worst-case row tiles

typedef __attribute__((ext_vector_type(4))) float f32x4;
typedef __attribute__((ext_vector_type(8))) short s16x8;

__device__ __forceinline__ unsigned short f2bf(float f) {
  unsigned u = __float_as_uint(f);
  return (unsigned short)((u + 0x7fffu + ((u >> 16) & 1u)) >> 16);
}
__device__ __forceinline__ float bf2f(unsigned short h) {
  return __uint_as_float(((unsigned)h) << 16);
}
// tanh-form GELU via hardware exp; |err| < ~1e-3, << threshold.
__device__ __forceinline__ float gelu_fast(float v) {
  float z = 1.5957691216057308f * (v + 0.044715f * v * v * v);
  return v / (1.0f + __expf(-z));
}
__device__ __forceinline__ void gl_lds16(const unsigned short* g, unsigned short* l) {
  __builtin_amdgcn_global_load_lds(
      (const __attribute__((address_space(1))) void*)g,
      (__attribute__((address_space(3))) void*)l, 16, 0, 0);
}

// ---------------- small kernels ----------------

// src [E][R][C] fp32 -> dst [E][C][R] bf16
__global__ __launch_bounds__(256) void k_transpose(
    const float* __restrict__ src, unsigned short* __restrict__ dst, int R, int C) {
  __shared__ float t[32][33];
  const int e = blockIdx.z;
  const float* S = src + (size_t)e * R * C;
  unsigned short* Dt = dst + (size_t)e * R * C;
  const int c0 = blockIdx.x * 32, r0 = blockIdx.y * 32;
  const int tx = threadIdx.x & 31, ty = threadIdx.x >> 5;  // ty 0..7
#pragma unroll
  for (int i = 0; i < 4; i++)
    t[ty + i * 8][tx] = S[(size_t)(r0 + ty + i * 8) * C + c0 + tx];
  __syncthreads();
#pragma unroll
  for (int i = 0; i < 4; i++)
    Dt[(size_t)(c0 + ty + i * 8) * R + r0 + tx] = f2bf(t[tx][ty + i * 8]);
}

// Wg [D][E] fp32 -> WgT [E][D] fp32 (32KB, LDS-staged)
__global__ __launch_bounds__(256) void k_wgt(const float* __restrict__ Wg,
                                             float* __restrict__ WgT) {
  __shared__ float lds[DD * EE];
  const int tid = threadIdx.x;
#pragma unroll
  for (int k = 0; k < 32; k++) lds[tid + 256 * k] = Wg[tid + 256 * k];
  __syncthreads();
#pragma unroll
  for (int k = 0; k < 32; k++) {
    int f = tid + 256 * k;                       // e = f>>10, d = f&1023
    WgT[f] = lds[(f & 1023) * 8 + (f >> 10)];
  }
}

// router: gates via lane-coalesced WgT rows; fused x -> bf16 cast.
__global__ __launch_bounds__(256) void k_router(
    const float* __restrict__ x, const float* __restrict__ WgT,
    const float* __restrict__ bg, int* __restrict__ tok_e,
    float* __restrict__ tok_w, unsigned short* __restrict__ xbf) {
  const int lane = threadIdx.x & 63, wid = threadIdx.x >> 6;
  const int t = blockIdx.x * 4 + wid;
  const float4* xr4 = (const float4*)(x + (size_t)t * DD);
  ushort4* xb4 = (ushort4*)(xbf + (size_t)t * DD);
  float4 xv[4];
#pragma unroll
  for (int i = 0; i < 4; i++) {
    xv[i] = xr4[i * 64 + lane];
    ushort4 h;
    h.x = f2bf(xv[i].x); h.y = f2bf(xv[i].y);
    h.z = f2bf(xv[i].z); h.w = f2bf(xv[i].w);
    xb4[i * 64 + lane] = h;
  }
  float g[8];
#pragma unroll
  for (int e = 0; e < 8; e++) {
    const float4* w4 = (const float4*)(WgT + (size_t)e * DD);
    float a = 0.f;
#pragma unroll
    for (int i = 0; i < 4; i++) {
      float4 wv = w4[i * 64 + lane];
      a += xv[i].x * wv.x + xv[i].y * wv.y + xv[i].z * wv.z + xv[i].w * wv.w;
    }
    g[e] = a;
  }
#pragma unroll
  for (int off = 32; off; off >>= 1)
#pragma unroll
    for (int e2 = 0; e2 < 8; e2++) g[e2] += __shfl_xor(g[e2], off);
  if (lane == 0) {
#pragma unroll
    for (int e2 = 0; e2 < 8; e2++) g[e2] += bg[e2];
    int e1 = 0;
#pragma unroll
    for (int e2 = 1; e2 < 8; e2++) if (g[e2] > g[e1]) e1 = e2;
    int es = (e1 == 0) ? 1 : 0;
#pragma unroll
    for (int e2 = 0; e2 < 8; e2++) if (e2 != e1 && g[e2] > g[es]) es = e2;
    float p2 = expf(g[es] - g[e1]);
    float invs = 1.0f / (1.0f + p2);
    tok_e[2 * t] = e1; tok_e[2 * t + 1] = es;
    tok_w[2 * t] = invs; tok_w[2 * t + 1] = p2 * invs;
  }
}

// ballot-based per-block counting (no atomics)
__global__ __launch_bounds__(256) void k_hist(
    const int* __restrict__ tok_e, int* __restrict__ lrank,
    int* __restrict__ blockHist) {
  __shared__ int waveCnt[4][8];
  __shared__ int waveBase[4][8];
  const int tid = threadIdx.x, lane = tid & 63, wid = tid >> 6;
  const int i = blockIdx.x * 256 + tid;
  const int e = tok_e[i];
  int rw = 0;
#pragma unroll
  for (int ex = 0; ex < 8; ex++) {
    unsigned long long m = __ballot(e == ex);
    if (e == ex) rw = __popcll(m & ((1ull << lane) - 1ull));
    if (lane == 0) waveCnt[wid][ex] = __popcll(m);
  }
  __syncthreads();
  if (tid < 8) {
    int a0 = waveCnt[0][tid], a1 = waveCnt[1][tid];
    int a2 = waveCnt[2][tid], a3 = waveCnt[3][tid];
    waveBase[0][tid] = 0;
    waveBase[1][tid] = a0;
    waveBase[2][tid] = a0 + a1;
    waveBase[3][tid] = a0 + a1 + a2;
    blockHist[blockIdx.x * 8 + tid] = a0 + a1 + a2 + a3;
  }
  __syncthreads();
  lrank[i] = waveBase[wid][e] + rw;
}

// wave-parallel scan: 8 waves, wave e scans blockHist[:,e] (128 values)
__global__ __launch_bounds__(512) void k_scan(
    const int* __restrict__ blockHist, int* __restrict__ blockBase,
    int* __restrict__ offs) {
  __shared__ int tot[8];
  const int e = threadIdx.x >> 6;   // wave = expert
  const int lane = threadIdx.x & 63;
  int v0 = blockHist[lane * 8 + e];
  int v1 = blockHist[(64 + lane) * 8 + e];
  int s0 = v0, s1 = v1;
#pragma unroll
  for (int off = 1; off < 64; off <<= 1) {
    int u0 = __shfl_up(s0, off), u1 = __shfl_up(s1, off);
    if (lane >= off) { s0 += u0; s1 += u1; }
  }
  int t0 = __shfl(s0, 63);
  blockBase[lane * 8 + e] = s0 - v0;
  blockBase[(64 + lane) * 8 + e] = t0 + s1 - v1;
  if (lane == 63) tot[e] = t0 + s1;
  __syncthreads();
  if (threadIdx.x == 0) {
    int acc = 0;
    offs[0] = 0;
#pragma unroll
    for (int e2 = 0; e2 < 8; e2++) {
      acc += (tot[e2] + 127) & ~127;
      offs[e2 + 1] = acc;
    }
  }
}

__global__ __launch_bounds__(256) void k_assign(
    const int* __restrict__ tok_e, const int* __restrict__ lrank,
    const int* __restrict__ blockBase, const int* __restrict__ offs,
    int* __restrict__ slot_token, int* __restrict__ token_slot) {
  const int i = blockIdx.x * 256 + threadIdx.x;
  const int e = tok_e[i];
  const int slot = offs[e] + blockBase[blockIdx.x * 8 + e] + lrank[i];
  slot_token[slot] = i >> 1;
  token_slot[i] = slot;
}

// ---------------- GEMM: 128x128xBK64, 4 waves, LDS DOUBLE-buffer ------------
// Counted vmcnt(8): wait tile t's 8 loads, keep t+1's 8 in flight across the
// whole compute phase (prologue stages t=0,1; stage(t+2) after read-release
// barrier). This is the round-2 shape re-tested with the CLEAN grid (flat
// nt-fastest + bijective XCD swizzle — rounds 3-5's tests were confounded by
// CU-aliased / mt-major grids). LDS 64KB -> 2 blocks/CU. XOR LDS swizzle.
// EPI==1: +b1, fast gelu. EPI==2: +b2 only (residual added in LN).
template <int K, bool GATHER, int EPI, int NOUT>
__global__ __launch_bounds__(256, 2) void k_gemm(
    const unsigned short* __restrict__ A, const unsigned short* __restrict__ Bt,
    const int* __restrict__ offs, const int* __restrict__ slot_token,
    const float* __restrict__ bias, unsigned short* __restrict__ Out) {
  __shared__ unsigned short sA[2][128 * 64];
  __shared__ unsigned short sB[2][128 * 64];
  constexpr int NCT = NOUT / 128;
  constexpr int NWG = MT_TILES * NCT;
  constexpr int CPX = NWG / 8;
  const int raw = blockIdx.x;
  const int bid = (raw & 7) * CPX + (raw >> 3);   // bijective XCD swizzle
  const int nt = bid % NCT;
  const int mt = bid / NCT;
  const int g0 = mt * 128;            // global padded slot row
  if (g0 >= offs[EE]) return;
  int e = 0;
  while (offs[e + 1] <= g0) ++e;
  const int col0 = nt * 128;
  const int tid = threadIdx.x;
  const int wid = tid >> 6;
  const int lane = tid & 63;

  // source col-chunk pre-swizzle: lane writes LDS slot (row=lane>>3, c=lane&7),
  // which must hold logical chunk (c ^ (row&7))  [XOR involution]
  const int swz = (((lane & 7) ^ ((lane >> 3) & 7))) * 8;
  const unsigned short* aptr[4];
  const unsigned short* bptr[4];
#pragma unroll
  for (int i = 0; i < 4; ++i) {
    int r = (i * 4 + wid) * 8 + (lane >> 3);
    int ar;
    if constexpr (GATHER) ar = slot_token[g0 + r] & (TT - 1);  // pad-safe
    else ar = g0 + r;
    aptr[i] = A + (size_t)ar * K + swz;
    bptr[i] = Bt + ((size_t)e * NOUT + (col0 + r)) * K + swz;
  }

  f32x4 acc[4][4];
#pragma unroll
  for (int m = 0; m < 4; m++)
#pragma unroll
    for (int n = 0; n < 4; n++) acc[m][n] = (f32x4){0.f, 0.f, 0.f, 0.f};

  const int wr = (wid >> 1) * 64;
  const int wc = (wid & 1) * 64;
  const int lrow = lane & 15;
  const int khalf = lane >> 4;   // 0..3
  const int sx = lrow & 7;       // read-side swizzle key (= row&7)

  auto stage = [&](int t, int buf) {
    const int k0 = t * 64;
#pragma unroll
    for (int i = 0; i < 4; ++i) {
      gl_lds16(aptr[i] + k0, &sA[buf][(i * 4 + wid) * 512]);
      gl_lds16(bptr[i] + k0, &sB[buf][(i * 4 + wid) * 512]);
    }
  };

  constexpr int NT = K / 64;
  stage(0, 0);
  stage(1, 1);
#pragma unroll 1
  for (int t = 0; t < NT; ++t) {
    if (t < NT - 1) {
      asm volatile("s_waitcnt vmcnt(8)" ::: "memory");  // t done, t+1 in flight
    } else {
      asm volatile("s_waitcnt vmcnt(0)" ::: "memory");
    }
    __builtin_amdgcn_s_barrier();
    const unsigned short* pA = &sA[t & 1][0];
    const unsigned short* pB = &sB[t & 1][0];
#pragma unroll
    for (int kk = 0; kk < 2; ++kk) {
      const int so = ((kk * 4 + khalf) ^ sx) * 8;
      s16x8 af[4], bfr[4];
#pragma unroll
      for (int m = 0; m < 4; m++)
        af[m] = *(const s16x8*)(pA + (wr + m * 16 + lrow) * 64 + so);
#pragma unroll
      for (int n = 0; n < 4; n++)
        bfr[n] = *(const s16x8*)(pB + (wc + n * 16 + lrow) * 64 + so);
#pragma unroll
      for (int m = 0; m < 4; m++)
#pragma unroll
        for (int n = 0; n < 4; n++)
          acc[m][n] = __builtin_amdgcn_mfma_f32_16x16x32_bf16(af[m], bfr[n], acc[m][n], 0, 0, 0);
    }
    __builtin_amdgcn_s_barrier();   // all waves released buf[t&1]
    if (t + 2 < NT) stage(t + 2, t & 1);
  }

  const float* bv = bias + (size_t)e * NOUT;
#pragma unroll
  for (int m = 0; m < 4; m++) {
    int r_base = wr + m * 16 + (khalf << 2);
#pragma unroll
    for (int j = 0; j < 4; j++) {
      int gr = g0 + r_base + j;
      size_t orow = (size_t)gr * NOUT;
#pragma unroll
      for (int n = 0; n < 4; n++) {
        int gc = col0 + wc + n * 16 + lrow;
        float v = acc[m][n][j] + bv[gc];
        if constexpr (EPI == 1) v = gelu_fast(v);
        Out[orow + gc] = f2bf(v);
      }
    }
  }
}

// -------- LN + residual + weighted combine, one block per token -------------
__global__ __launch_bounds__(256) void k_ln(
    const unsigned short* __restrict__ y, const unsigned short* __restrict__ xbf,
    const int* __restrict__ token_slot, const int* __restrict__ tok_e,
    const float* __restrict__ tok_w, const float* __restrict__ gamma,
    const float* __restrict__ beta, float* __restrict__ out) {
  const int t = blockIdx.x;
  const int tid = threadIdx.x;
  const int lane = tid & 63, wid = tid >> 6;
  __shared__ float red[8];
  ushort4 xu = ((const ushort4*)(xbf + (size_t)t * DD))[tid];
  float x0 = bf2f(xu.x), x1 = bf2f(xu.y), x2 = bf2f(xu.z), x3 = bf2f(xu.w);
  float o0 = 0, o1 = 0, o2 = 0, o3 = 0;
#pragma unroll
  for (int k = 0; k < 2; k++) {
    int slot = token_slot[2 * t + k];
    int e = tok_e[2 * t + k];
    float w = tok_w[2 * t + k];
    ushort4 raw = ((const ushort4*)(y + (size_t)slot * DD))[tid];
    float v0 = bf2f(raw.x) + x0, v1 = bf2f(raw.y) + x1;
    float v2 = bf2f(raw.z) + x2, v3 = bf2f(raw.w) + x3;
    float s = v0 + v1 + v2 + v3;
    float s2 = v0 * v0 + v1 * v1 + v2 * v2 + v3 * v3;
#pragma unroll
    for (int off = 32; off; off >>= 1) {
      s += __shfl_xor(s, off);
      s2 += __shfl_xor(s2, off);
    }
    if (lane == 0) { red[wid] = s; red[4 + wid] = s2; }
    __syncthreads();
    s = red[0] + red[1] + red[2] + red[3];
    s2 = red[4] + red[5] + red[6] + red[7];
    float mu = s * (1.0f / 1024.0f);
    float var = s2 * (1.0f / 1024.0f) - mu * mu;
    float inv = rsqrtf(var + 1e-5f);
    float4 g4 = ((const float4*)(gamma + (size_t)e * DD))[tid];
    float4 b4 = ((const float4*)(beta + (size_t)e * DD))[tid];
    o0 += w * ((v0 - mu) * inv * g4.x + b4.x);
    o1 += w * ((v1 - mu) * inv * g4.y + b4.y);
    o2 += w * ((v2 - mu) * inv * g4.z + b4.z);
    o3 += w * ((v3 - mu) * inv * g4.w + b4.w);
    __syncthreads();
  }
  float4 r;
  r.x = o0; r.y = o1; r.z = o2; r.w = o3;
  ((float4*)(out + (size_t)t * DD))[tid] = r;
}

// ---------------- launch ----------------

extern "C" void kernel_launch(void* const* d_in, const int* in_sizes, int n_in,
                              void* d_out, int out_size, void* d_ws, size_t ws_size,
                              hipStream_t stream) {
  const float* x = (const float*)d_in[0];
  const float* Wg = (const float*)d_in[1];
  const float* bg = (const float*)d_in[2];
  const float* W1 = (const float*)d_in[3];
  const float* b1 = (const float*)d_in[4];
  const float* W2 = (const float*)d_in[5];
  const float* b2 = (const float*)d_in[6];
  const float* gamma = (const float*)d_in[7];
  const float* beta = (const float*)d_in[8];
  float* out = (float*)d_out;

  char* ws = (char*)d_ws;
  size_t o = 0;
  auto take = [&](size_t b) -> void* {
    void* p = ws + o;
    o += (b + 255) & ~(size_t)255;
    return p;
  };
  int* offs = (int*)take((EE + 1) * 4);
  int* tok_e = (int*)take(NA * 4);
  int* lrank = (int*)take(NA * 4);
  int* token_slot = (int*)take(NA * 4);
  float* tok_w = (float*)take(NA * 4);
  int* blockHist = (int*)take(NBLK * EE * 4);
  int* blockBase = (int*)take(NBLK * EE * 4);
  int* slot_token = (int*)take(SLOT_CAP * 4);
  float* WgT = (float*)take((size_t)EE * DD * 4);
  unsigned short* xbf = (unsigned short*)take((size_t)TT * DD * 2);
  unsigned short* W1t = (unsigned short*)take((size_t)EE * HH * DD * 2);
  unsigned short* W2t = (unsigned short*)take((size_t)EE * DD * HH * 2);
  unsigned short* hbuf = (unsigned short*)take((size_t)SLOT_CAP * HH * 2);
  unsigned short* ybuf = (unsigned short*)take((size_t)SLOT_CAP * DD * 2);
  if (o > ws_size) return;  // workspace too small — bail (visible as failure)

  // W1 [E][D][H] -> W1t [E][H][D]
  k_transpose<<<dim3(HH / 32, DD / 32, EE), 256, 0, stream>>>(W1, W1t, DD, HH);
  // W2 [E][H][D] -> W2t [E][D][H]
  k_transpose<<<dim3(DD / 32, HH / 32, EE), 256, 0, stream>>>(W2, W2t, HH, DD);
  k_wgt<<<1, 256, 0, stream>>>(Wg, WgT);
  k_router<<<TT / 4, 256, 0, stream>>>(x, WgT, bg, tok_e, tok_w, xbf);
  k_hist<<<NBLK, 256, 0, stream>>>(tok_e, lrank, blockHist);
  k_scan<<<1, 512, 0, stream>>>(blockHist, blockBase, offs);
  k_assign<<<NBLK, 256, 0, stream>>>(tok_e, lrank, blockBase, offs, slot_token,
                                     token_slot);
  // GEMM1: h = gelu(x_bf @ W1 + b1), gathered rows, K=1024, N=512
  k_gemm<1024, true, 1, 512><<<MT_TILES * (512 / 128), 256, 0, stream>>>(
      xbf, W1t, offs, slot_token, b1, hbuf);
  // GEMM2: y' = h @ W2 + b2 (residual added in LN), K=512, N=1024
  k_gemm<512, false, 2, 1024><<<MT_TILES * (1024 / 128), 256, 0, stream>>>(
      hbuf, W2t, offs, slot_token, b2, ybuf);
  k_ln<<<TT, 256, 0, stream>>>(ybuf, xbf, token_slot, tok_e, tok_w, gamma, beta,
                               out);
}

// Round 12
// 172.473 us; speedup vs baseline: 1.1900x; 1.1900x over previous
//
#include <hip/hip_runtime.h>

#define TT 16384      // tokens
#define DD 1024
#define HH 512
#define EE 8
#define NA (2*TT)                  // assignments
#define NBLK (NA/256)              // 128 hist blocks
#define SLOT_CAP (NA + EE*128)     // 33792
#define MT_TILES (SLOT_CAP/128)    // 264 worst-case row tiles

typedef __attribute__((ext_vector_type(4))) float f32x4;
typedef __attribute__((ext_vector_type(8))) short s16x8;

__device__ __forceinline__ unsigned short f2bf(float f) {
  unsigned u = __float_as_uint(f);
  return (unsigned short)((u + 0x7fffu + ((u >> 16) & 1u)) >> 16);
}
__device__ __forceinline__ float bf2f(unsigned short h) {
  return __uint_as_float(((unsigned)h) << 16);
}
// tanh-form GELU via hardware exp; |err| < ~1e-3, << threshold.
__device__ __forceinline__ float gelu_fast(float v) {
  float z = 1.5957691216057308f * (v + 0.044715f * v * v * v);
  return v / (1.0f + __expf(-z));
}
__device__ __forceinline__ void gl_lds16(const unsigned short* g, unsigned short* l) {
  __builtin_amdgcn_global_load_lds(
      (const __attribute__((address_space(1))) void*)g,
      (__attribute__((address_space(3))) void*)l, 16, 0, 0);
}

// ---------------- fused prep: router + W1^T + W2^T (independent work, ------
// one launch so transposes fill CUs concurrently with the router instead of
// serializing on the stream). Router blocks first (long pole).
// grid: [0,4096) router (4 tokens/block); [4096,8192) W1 transpose;
//       [8192,12288) W2 transpose.
__global__ __launch_bounds__(256) void k_prep(
    const float* __restrict__ x, const float* __restrict__ Wg,
    const float* __restrict__ bg, int* __restrict__ tok_e,
    float* __restrict__ tok_w, unsigned short* __restrict__ xbf,
    const float* __restrict__ W1, unsigned short* __restrict__ W1t,
    const float* __restrict__ W2, unsigned short* __restrict__ W2t) {
  __shared__ float sh[DD * EE];   // 32KB: router Wg-stage / transpose tile
  const int tid = threadIdx.x;
  const int bidx = blockIdx.x;

  if (bidx < TT / 4) {
    // ---- router: stage Wg [D][E] -> sh [E][D] (coalesced read, one-time) --
#pragma unroll
    for (int k = 0; k < 32; k++) {
      int f = tid + 256 * k;                    // f = d*8 + e
      sh[(f & 7) * DD + (f >> 3)] = Wg[f];
    }
    __syncthreads();
    const int lane = tid & 63, wid = tid >> 6;
    const int t = bidx * 4 + wid;
    const float4* xr4 = (const float4*)(x + (size_t)t * DD);
    ushort4* xb4 = (ushort4*)(xbf + (size_t)t * DD);
    float4 xv[4];
#pragma unroll
    for (int i = 0; i < 4; i++) {
      xv[i] = xr4[i * 64 + lane];
      ushort4 h;
      h.x = f2bf(xv[i].x); h.y = f2bf(xv[i].y);
      h.z = f2bf(xv[i].z); h.w = f2bf(xv[i].w);
      xb4[i * 64 + lane] = h;
    }
    float g[8];
#pragma unroll
    for (int e = 0; e < 8; e++) {
      const float4* w4 = (const float4*)(sh + (size_t)e * DD);
      float a = 0.f;
#pragma unroll
      for (int i = 0; i < 4; i++) {
        float4 wv = w4[i * 64 + lane];
        a += xv[i].x * wv.x + xv[i].y * wv.y + xv[i].z * wv.z + xv[i].w * wv.w;
      }
      g[e] = a;
    }
#pragma unroll
    for (int off = 32; off; off >>= 1)
#pragma unroll
      for (int e2 = 0; e2 < 8; e2++) g[e2] += __shfl_xor(g[e2], off);
    if (lane == 0) {
#pragma unroll
      for (int e2 = 0; e2 < 8; e2++) g[e2] += bg[e2];
      int e1 = 0;
#pragma unroll
      for (int e2 = 1; e2 < 8; e2++) if (g[e2] > g[e1]) e1 = e2;
      int es = (e1 == 0) ? 1 : 0;
#pragma unroll
      for (int e2 = 0; e2 < 8; e2++) if (e2 != e1 && g[e2] > g[es]) es = e2;
      float p2 = expf(g[es] - g[e1]);
      float invs = 1.0f / (1.0f + p2);
      tok_e[2 * t] = e1; tok_e[2 * t + 1] = es;
      tok_w[2 * t] = invs; tok_w[2 * t + 1] = p2 * invs;
    }
    return;
  }

  // ---- transposes: src [E][R][C] fp32 -> dst [E][C][R] bf16 ----
  const float* S;
  unsigned short* Dt;
  int R, C, idx;
  if (bidx < TT / 4 + 4096) {           // W1: R=DD, C=HH, grid 16x32x8
    idx = bidx - TT / 4;
    R = DD; C = HH;
    int e = idx >> 9;
    S = W1 + (size_t)e * R * C;
    Dt = W1t + (size_t)e * R * C;
    idx &= 511;
  } else {                              // W2: R=HH, C=DD, grid 32x16x8
    idx = bidx - TT / 4 - 4096;
    R = HH; C = DD;
    int e = idx >> 9;
    S = W2 + (size_t)e * R * C;
    Dt = W2t + (size_t)e * R * C;
    idx &= 511;
  }
  const int nbx = C / 32;
  const int c0 = (idx % nbx) * 32, r0 = (idx / nbx) * 32;
  float (*tt)[33] = (float(*)[33])sh;
  const int tx = tid & 31, ty = tid >> 5;  // ty 0..7
#pragma unroll
  for (int i = 0; i < 4; i++)
    tt[ty + i * 8][tx] = S[(size_t)(r0 + ty + i * 8) * C + c0 + tx];
  __syncthreads();
#pragma unroll
  for (int i = 0; i < 4; i++)
    Dt[(size_t)(c0 + ty + i * 8) * R + r0 + tx] = f2bf(tt[tx][ty + i * 8]);
}

// ballot-based per-block counting (no atomics)
__global__ __launch_bounds__(256) void k_hist(
    const int* __restrict__ tok_e, int* __restrict__ lrank,
    int* __restrict__ blockHist) {
  __shared__ int waveCnt[4][8];
  __shared__ int waveBase[4][8];
  const int tid = threadIdx.x, lane = tid & 63, wid = tid >> 6;
  const int i = blockIdx.x * 256 + tid;
  const int e = tok_e[i];
  int rw = 0;
#pragma unroll
  for (int ex = 0; ex < 8; ex++) {
    unsigned long long m = __ballot(e == ex);
    if (e == ex) rw = __popcll(m & ((1ull << lane) - 1ull));
    if (lane == 0) waveCnt[wid][ex] = __popcll(m);
  }
  __syncthreads();
  if (tid < 8) {
    int a0 = waveCnt[0][tid], a1 = waveCnt[1][tid];
    int a2 = waveCnt[2][tid], a3 = waveCnt[3][tid];
    waveBase[0][tid] = 0;
    waveBase[1][tid] = a0;
    waveBase[2][tid] = a0 + a1;
    waveBase[3][tid] = a0 + a1 + a2;
    blockHist[blockIdx.x * 8 + tid] = a0 + a1 + a2 + a3;
  }
  __syncthreads();
  lrank[i] = waveBase[wid][e] + rw;
}

// wave-parallel scan: 8 waves, wave e scans blockHist[:,e] (128 values)
__global__ __launch_bounds__(512) void k_scan(
    const int* __restrict__ blockHist, int* __restrict__ blockBase,
    int* __restrict__ offs) {
  __shared__ int tot[8];
  const int e = threadIdx.x >> 6;   // wave = expert
  const int lane = threadIdx.x & 63;
  int v0 = blockHist[lane * 8 + e];
  int v1 = blockHist[(64 + lane) * 8 + e];
  int s0 = v0, s1 = v1;
#pragma unroll
  for (int off = 1; off < 64; off <<= 1) {
    int u0 = __shfl_up(s0, off), u1 = __shfl_up(s1, off);
    if (lane >= off) { s0 += u0; s1 += u1; }
  }
  int t0 = __shfl(s0, 63);
  blockBase[lane * 8 + e] = s0 - v0;
  blockBase[(64 + lane) * 8 + e] = t0 + s1 - v1;
  if (lane == 63) tot[e] = t0 + s1;
  __syncthreads();
  if (threadIdx.x == 0) {
    int acc = 0;
    offs[0] = 0;
#pragma unroll
    for (int e2 = 0; e2 < 8; e2++) {
      acc += (tot[e2] + 127) & ~127;
      offs[e2 + 1] = acc;
    }
  }
}

__global__ __launch_bounds__(256) void k_assign(
    const int* __restrict__ tok_e, const int* __restrict__ lrank,
    const int* __restrict__ blockBase, const int* __restrict__ offs,
    int* __restrict__ slot_token, int* __restrict__ token_slot) {
  const int i = blockIdx.x * 256 + threadIdx.x;
  const int e = tok_e[i];
  const int slot = offs[e] + blockBase[blockIdx.x * 8 + e] + lrank[i];
  slot_token[slot] = i >> 1;
  token_slot[i] = slot;
}

// ---------------- GEMM: 128x128xBK64, 4 waves, m97 single-buffer loop -------
// (round-10 structure — best measured: 54.5us/GEMM, ~650 TF. dbuf+counted
// vmcnt tested 4x (r2/3/4/11), always worse: occupancy loss > pipeline gain.)
// LDS 32KB; launch_bounds(256,4) = exact VGPR fit (60 arch + 64 acc, no
// spill). Flat 1-D grid, nt-fastest, bijective XCD swizzle, XOR LDS swizzle.
// EPI==1: +b1, fast gelu. EPI==2: +b2 only (residual added in LN).
template <int K, bool GATHER, int EPI, int NOUT>
__global__ __launch_bounds__(256, 4) void k_gemm(
    const unsigned short* __restrict__ A, const unsigned short* __restrict__ Bt,
    const int* __restrict__ offs, const int* __restrict__ slot_token,
    const float* __restrict__ bias, unsigned short* __restrict__ Out) {
  __shared__ unsigned short sA[128 * 64];
  __shared__ unsigned short sB[128 * 64];
  constexpr int NCT = NOUT / 128;
  constexpr int NWG = MT_TILES * NCT;
  constexpr int CPX = NWG / 8;
  const int raw = blockIdx.x;
  const int bid = (raw & 7) * CPX + (raw >> 3);   // bijective XCD swizzle
  const int nt = bid % NCT;
  const int mt = bid / NCT;
  const int g0 = mt * 128;            // global padded slot row
  if (g0 >= offs[EE]) return;
  int e = 0;
  while (offs[e + 1] <= g0) ++e;
  const int col0 = nt * 128;
  const int tid = threadIdx.x;
  const int wid = tid >> 6;
  const int lane = tid & 63;

  // source col-chunk pre-swizzle: lane writes LDS slot (row=lane>>3, c=lane&7),
  // which must hold logical chunk (c ^ (row&7))  [XOR involution]
  const int swz = (((lane & 7) ^ ((lane >> 3) & 7))) * 8;
  const unsigned short* aptr[4];
  const unsigned short* bptr[4];
#pragma unroll
  for (int i = 0; i < 4; ++i) {
    int r = (i * 4 + wid) * 8 + (lane >> 3);
    int ar;
    if constexpr (GATHER) ar = slot_token[g0 + r] & (TT - 1);  // pad-safe
    else ar = g0 + r;
    aptr[i] = A + (size_t)ar * K + swz;
    bptr[i] = Bt + ((size_t)e * NOUT + (col0 + r)) * K + swz;
  }

  f32x4 acc[4][4];
#pragma unroll
  for (int m = 0; m < 4; m++)
#pragma unroll
    for (int n = 0; n < 4; n++) acc[m][n] = (f32x4){0.f, 0.f, 0.f, 0.f};

  const int wr = (wid >> 1) * 64;
  const int wc = (wid & 1) * 64;
  const int lrow = lane & 15;
  const int khalf = lane >> 4;   // 0..3
  const int sx = lrow & 7;       // read-side swizzle key (= row&7)

  constexpr int NT = K / 64;
#pragma unroll 1
  for (int t = 0; t < NT; ++t) {
    const int k0 = t * 64;
#pragma unroll
    for (int i = 0; i < 4; ++i) {
      gl_lds16(aptr[i] + k0, sA + (i * 4 + wid) * 512);
      gl_lds16(bptr[i] + k0, sB + (i * 4 + wid) * 512);
    }
    __syncthreads();   // drains vmcnt -> staged tile visible
#pragma unroll
    for (int kk = 0; kk < 2; ++kk) {
      const int so = ((kk * 4 + khalf) ^ sx) * 8;
      s16x8 af[4], bfr[4];
#pragma unroll
      for (int m = 0; m < 4; m++)
        af[m] = *(const s16x8*)(sA + (wr + m * 16 + lrow) * 64 + so);
#pragma unroll
      for (int n = 0; n < 4; n++)
        bfr[n] = *(const s16x8*)(sB + (wc + n * 16 + lrow) * 64 + so);
#pragma unroll
      for (int m = 0; m < 4; m++)
#pragma unroll
        for (int n = 0; n < 4; n++)
          acc[m][n] = __builtin_amdgcn_mfma_f32_16x16x32_bf16(af[m], bfr[n], acc[m][n], 0, 0, 0);
    }
    __syncthreads();   // all waves done reading before next stage overwrites
  }

  const float* bv = bias + (size_t)e * NOUT;
#pragma unroll
  for (int m = 0; m < 4; m++) {
    int r_base = wr + m * 16 + (khalf << 2);
#pragma unroll
    for (int j = 0; j < 4; j++) {
      int gr = g0 + r_base + j;
      size_t orow = (size_t)gr * NOUT;
#pragma unroll
      for (int n = 0; n < 4; n++) {
        int gc = col0 + wc + n * 16 + lrow;
        float v = acc[m][n][j] + bv[gc];
        if constexpr (EPI == 1) v = gelu_fast(v);
        Out[orow + gc] = f2bf(v);
      }
    }
  }
}

// -------- LN + residual + weighted combine, one block per token -------------
__global__ __launch_bounds__(256) void k_ln(
    const unsigned short* __restrict__ y, const unsigned short* __restrict__ xbf,
    const int* __restrict__ token_slot, const int* __restrict__ tok_e,
    const float* __restrict__ tok_w, const float* __restrict__ gamma,
    const float* __restrict__ beta, float* __restrict__ out) {
  const int t = blockIdx.x;
  const int tid = threadIdx.x;
  const int lane = tid & 63, wid = tid >> 6;
  __shared__ float red[8];
  ushort4 xu = ((const ushort4*)(xbf + (size_t)t * DD))[tid];
  float x0 = bf2f(xu.x), x1 = bf2f(xu.y), x2 = bf2f(xu.z), x3 = bf2f(xu.w);
  float o0 = 0, o1 = 0, o2 = 0, o3 = 0;
#pragma unroll
  for (int k = 0; k < 2; k++) {
    int slot = token_slot[2 * t + k];
    int e = tok_e[2 * t + k];
    float w = tok_w[2 * t + k];
    ushort4 raw = ((const ushort4*)(y + (size_t)slot * DD))[tid];
    float v0 = bf2f(raw.x) + x0, v1 = bf2f(raw.y) + x1;
    float v2 = bf2f(raw.z) + x2, v3 = bf2f(raw.w) + x3;
    float s = v0 + v1 + v2 + v3;
    float s2 = v0 * v0 + v1 * v1 + v2 * v2 + v3 * v3;
#pragma unroll
    for (int off = 32; off; off >>= 1) {
      s += __shfl_xor(s, off);
      s2 += __shfl_xor(s2, off);
    }
    if (lane == 0) { red[wid] = s; red[4 + wid] = s2; }
    __syncthreads();
    s = red[0] + red[1] + red[2] + red[3];
    s2 = red[4] + red[5] + red[6] + red[7];
    float mu = s * (1.0f / 1024.0f);
    float var = s2 * (1.0f / 1024.0f) - mu * mu;
    float inv = rsqrtf(var + 1e-5f);
    float4 g4 = ((const float4*)(gamma + (size_t)e * DD))[tid];
    float4 b4 = ((const float4*)(beta + (size_t)e * DD))[tid];
    o0 += w * ((v0 - mu) * inv * g4.x + b4.x);
    o1 += w * ((v1 - mu) * inv * g4.y + b4.y);
    o2 += w * ((v2 - mu) * inv * g4.z + b4.z);
    o3 += w * ((v3 - mu) * inv * g4.w + b4.w);
    __syncthreads();
  }
  float4 r;
  r.x = o0; r.y = o1; r.z = o2; r.w = o3;
  ((float4*)(out + (size_t)t * DD))[tid] = r;
}

// ---------------- launch ----------------

extern "C" void kernel_launch(void* const* d_in, const int* in_sizes, int n_in,
                              void* d_out, int out_size, void* d_ws, size_t ws_size,
                              hipStream_t stream) {
  const float* x = (const float*)d_in[0];
  const float* Wg = (const float*)d_in[1];
  const float* bg = (const float*)d_in[2];
  const float* W1 = (const float*)d_in[3];
  const float* b1 = (const float*)d_in[4];
  const float* W2 = (const float*)d_in[5];
  const float* b2 = (const float*)d_in[6];
  const float* gamma = (const float*)d_in[7];
  const float* beta = (const float*)d_in[8];
  float* out = (float*)d_out;

  char* ws = (char*)d_ws;
  size_t o = 0;
  auto take = [&](size_t b) -> void* {
    void* p = ws + o;
    o += (b + 255) & ~(size_t)255;
    return p;
  };
  int* offs = (int*)take((EE + 1) * 4);
  int* tok_e = (int*)take(NA * 4);
  int* lrank = (int*)take(NA * 4);
  int* token_slot = (int*)take(NA * 4);
  float* tok_w = (float*)take(NA * 4);
  int* blockHist = (int*)take(NBLK * EE * 4);
  int* blockBase = (int*)take(NBLK * EE * 4);
  int* slot_token = (int*)take(SLOT_CAP * 4);
  unsigned short* xbf = (unsigned short*)take((size_t)TT * DD * 2);
  unsigned short* W1t = (unsigned short*)take((size_t)EE * HH * DD * 2);
  unsigned short* W2t = (unsigned short*)take((size_t)EE * DD * HH * 2);
  unsigned short* hbuf = (unsigned short*)take((size_t)SLOT_CAP * HH * 2);
  unsigned short* ybuf = (unsigned short*)take((size_t)SLOT_CAP * DD * 2);
  if (o > ws_size) return;  // workspace too small — bail (visible as failure)

  // fused prep: router (blocks 0..4095) + W1^T + W2^T concurrently
  k_prep<<<TT / 4 + 8192, 256, 0, stream>>>(x, Wg, bg, tok_e, tok_w, xbf,
                                            W1, W1t, W2, W2t);
  k_hist<<<NBLK, 256, 0, stream>>>(tok_e, lrank, blockHist);
  k_scan<<<1, 512, 0, stream>>>(blockHist, blockBase, offs);
  k_assign<<<NBLK, 256, 0, stream>>>(tok_e, lrank, blockBase, offs, slot_token,
                                     token_slot);
  // GEMM1: h = gelu(x_bf @ W1 + b1), gathered rows, K=1024, N=512
  k_gemm<1024, true, 1, 512><<<MT_TILES * (512 / 128), 256, 0, stream>>>(
      xbf, W1t, offs, slot_token, b1, hbuf);
  // GEMM2: y' = h @ W2 + b2 (residual added in LN), K=512, N=1024
  k_gemm<512, false, 2, 1024><<<MT_TILES * (1024 / 128), 256, 0, stream>>>(
      hbuf, W2t, offs, slot_token, b2, ybuf);
  k_ln<<<TT, 256, 0, stream>>>(ybuf, xbf, token_slot, tok_e, tok_w, gamma, beta,
                               out);
}